// Round 7
// baseline (61041.675 us; speedup 1.0000x reference)
//
#include <hip/hip_runtime.h>
#include <hip/hip_fp16.h>

#define B_ 256
#define S_ 512
#define F_ 64
#define H_ 1024
#define O_ 24
#define G_ 4096  // 4*H
#define NBLK 512

typedef _Float16 half_t;
typedef _Float16 h8 __attribute__((ext_vector_type(8)));
typedef float f4 __attribute__((ext_vector_type(4)));

// ---- workspace layout (bytes) ----
// zeroed region first:
#define OFF_H1 ((size_t)0)                                   // 2*B*H halfs (ping-pong)
#define OFF_H2 (OFF_H1 + (size_t)2*B_*H_*2)
#define OFF_C1 (OFF_H2 + (size_t)2*B_*H_*2)                  // B*H f32
#define OFF_C2 (OFF_C1 + (size_t)B_*H_*4)
#define OFF_OP (OFF_C2 + (size_t)B_*H_*4)                    // out_part [32][B][O] f32
#define OFF_BAR (OFF_OP + (size_t)32*B_*O_*4)                // 2 ints: barrier count, gen
#define ZBYTES (OFF_BAR + 256)
// non-zeroed (overwritten every launch):
#define OFF_BIAS0 (ZBYTES)
#define OFF_BIAS1 (OFF_BIAS0 + (size_t)G_*4)
#define OFF_XH    (OFF_BIAS1 + (size_t)G_*4)                 // B*S*F halfs
#define OFF_WIH0  (OFF_XH + (size_t)B_*S_*F_*2)              // packed, G*F halfs
#define OFF_WHH0  (OFF_WIH0 + (size_t)G_*F_*2)               // packed, G*H halfs
#define OFF_WIH1  (OFF_WHH0 + (size_t)G_*H_*2)
#define OFF_WHH1  (OFF_WIH1 + (size_t)G_*H_*2)
#define WS_NEEDED (OFF_WHH1 + (size_t)G_*H_*2)               // ~47.5 MB

__global__ void k_bias(const float* __restrict__ bi0, const float* __restrict__ bh0,
                       const float* __restrict__ bi1, const float* __restrict__ bh1,
                       float* __restrict__ bias0, float* __restrict__ bias1) {
    int i = blockIdx.x * blockDim.x + threadIdx.x;
    if (i < G_) { bias0[i] = bi0[i] + bh0[i]; bias1[i] = bi1[i] + bh1[i]; }
}

__global__ void k_cvt(const float* __restrict__ src, half_t* __restrict__ dst, int n) {
    int i = blockIdx.x * blockDim.x + threadIdx.x;
    int stride = gridDim.x * blockDim.x;
    for (; i < n; i += stride) dst[i] = (half_t)src[i];
}

// Pack W [4H, NC*64] f32 -> fp16 MFMA-fragment order:
// dst h8 index i = (((g*32+ht)*NC + ck)*4 + j)*64 + lane, j = colhalf*2 + kshalf
__global__ void k_pack(const float* __restrict__ src, half_t* __restrict__ dst, int NC) {
    int i = blockIdx.x * blockDim.x + threadIdx.x;
    int total = 32768 * NC;          // 4*32*NC*4*64
    if (i >= total) return;
    int lane = i & 63;
    int j    = (i >> 6) & 3;
    int ck   = (i >> 8) % NC;
    int gh   = i / (256 * NC);       // g*32+ht, 0..127
    int srow = (gh >> 5) * H_ + (gh & 31) * 32 + (j >> 1) * 16 + (lane & 15);
    int scol = ck * 64 + (j & 1) * 32 + (lane >> 4) * 8;
    const float* s = src + (size_t)srow * (NC * 64) + scol;
    h8 v;
    #pragma unroll
    for (int e = 0; e < 8; ++e) v[e] = (half_t)s[e];
    *(h8*)&dst[(size_t)i * 8] = v;
}

// Device-scope grid barrier (generation counter). AGENT-scope acq/rel atomics
// emit the cache writeback/invalidate needed for cross-XCD visibility (G16).
// Safe only because all NBLK blocks are co-resident: 512 blocks = 2/CU at
// __launch_bounds__(256,2), 25.7 KB LDS, ~110 VGPR — comfortably fits.
__device__ __forceinline__ void grid_barrier(int* cnt, int* gen) {
    __syncthreads();
    if (threadIdx.x == 0) {
        __threadfence();   // release prior global writes to device scope
        int g = __hip_atomic_load(gen, __ATOMIC_RELAXED, __HIP_MEMORY_SCOPE_AGENT);
        int v = __hip_atomic_fetch_add(cnt, 1, __ATOMIC_ACQ_REL, __HIP_MEMORY_SCOPE_AGENT);
        if (v == NBLK - 1) {
            __hip_atomic_store(cnt, 0, __ATOMIC_RELAXED, __HIP_MEMORY_SCOPE_AGENT);
            __hip_atomic_store(gen, g + 1, __ATOMIC_RELEASE, __HIP_MEMORY_SCOPE_AGENT);
        } else {
            while (__hip_atomic_load(gen, __ATOMIC_ACQUIRE, __HIP_MEMORY_SCOPE_AGENT) == g)
                __builtin_amdgcn_s_sleep(2);
        }
    }
    __syncthreads();
}

// Persistent fused kernel: ONE launch runs all 513 phases (phase t = layer0
// step t by blocks 256..511, layer1 step t-1 by blocks 0..255), separated by
// the grid barrier. Inner phase body = the best-measured (R3) structure:
// packed fragment-order W direct global->VGPR (1KB coalesced per instr,
// L2-resident via ht%8==XCD map), cooperative single-buffered LDS A staging,
// two __syncthreads per chunk. Prefetch in NAMED registers only (runtime-
// indexed local arrays go to scratch: round-3's 55x cliff).
__global__ __launch_bounds__(256, 2)
void k_persist(const half_t* __restrict__ x_h,
               const half_t* __restrict__ Wih0, const half_t* __restrict__ Whh0,
               const float* __restrict__ bias0, float* __restrict__ c1g, half_t* __restrict__ h1buf,
               const half_t* __restrict__ Wih1, const half_t* __restrict__ Whh1,
               const float* __restrict__ bias1, float* __restrict__ c2g, half_t* __restrict__ h2buf,
               const float* __restrict__ fcW, float* __restrict__ out_part,
               int* bar_cnt, int* bar_gen)
{
    __shared__ __align__(16) half_t A_s[32 * 72];
    __shared__ float gate_s[4][32 * 33];
    __shared__ float h_s[32 * 33];

    const int n  = blockIdx.x;
    const bool l1 = (n < 256);
    const int m  = l1 ? n : n - 256;
    const int ht = (m & 7) + 8 * ((m >> 3) & 3);   // ht % 8 == linear_id % 8 (XCD-resident W)
    const int bt = (m >> 5) & 7;

    const int thr  = threadIdx.x;
    const int wave = thr >> 6, lane = thr & 63;
    const int quad = lane >> 4, l15 = lane & 15;
    const int hbase = ht * 32;
    const int ghW = wave * 32 + ht;         // packed-W (gate,ht) group
    const int ar  = thr >> 3;               // A staging row 0..31
    const int ak  = (thr & 7) * 8;          // A staging k-offset

    // layer-fixed state
    const half_t *Wih, *Whh; const float* bias; float* c; int cx;
    if (l1) { Wih = Wih1; Whh = Whh1; bias = bias1; c = c2g; cx = 16; }
    else    { Wih = Wih0; Whh = Whh0; bias = bias0; c = c1g; cx = 1;  }
    const int nchunks = cx + 16;

    const float bv0 = bias[wave * H_ + hbase + l15];
    const float bv1 = bias[wave * H_ + hbase + 16 + l15];

    for (int t = 0; t <= S_; ++t) {
        const bool active = l1 ? (t > 0) : (t < S_);
        if (active) {
            const int tt = l1 ? t - 1 : t;
            const half_t* xb; int ldx; const half_t* hp; half_t* hn_out;
            if (l1) {
                xb = h1buf + (size_t)(tt & 1) * B_ * H_;  ldx = H_;
                hp     = h2buf + (size_t)((tt - 1) & 1) * B_ * H_;
                hn_out = h2buf + (size_t)(tt & 1) * B_ * H_;
            } else {
                xb = x_h + (size_t)tt * F_;  ldx = S_ * F_;
                hp     = h1buf + (size_t)((tt - 1) & 1) * B_ * H_;
                hn_out = h1buf + (size_t)(tt & 1) * B_ * H_;
            }

            f4 acc[2][2];
            #pragma unroll
            for (int mt = 0; mt < 2; ++mt) {
                acc[mt][0] = (f4){bv0, bv0, bv0, bv0};
                acc[mt][1] = (f4){bv1, bv1, bv1, bv1};
            }

            f4 pA;
            h8 c0, c1r, c2r, c3;   // current W fragments
            h8 n0, n1, n2, n3;     // next

            auto fetchA = [&](int ck) {
                const half_t* Ab; int lda, k0;
                if (ck < cx) { Ab = xb; lda = ldx; k0 = ck * 64; }
                else         { Ab = hp; lda = H_;  k0 = (ck - cx) * 64; }
                pA = *(const f4*)&Ab[(size_t)(bt * 32 + ar) * lda + k0 + ak];
            };
            auto fetchW = [&](int ck, h8& r0, h8& r1, h8& r2, h8& r3) {
                const half_t* Wb; int ckk, NC;
                if (ck < cx) { Wb = Wih; ckk = ck;      NC = cx; }
                else         { Wb = Whh; ckk = ck - cx; NC = 16; }
                const half_t* base = Wb + ((size_t)(((ghW * NC) + ckk) * 4) * 64 + lane) * 8;
                r0 = *(const h8*)(base + 0 * 512);
                r1 = *(const h8*)(base + 1 * 512);
                r2 = *(const h8*)(base + 2 * 512);
                r3 = *(const h8*)(base + 3 * 512);
            };

            fetchA(0);
            fetchW(0, c0, c1r, c2r, c3);
            for (int ck = 0; ck < nchunks; ++ck) {
                *(f4*)&A_s[ar * 72 + ak] = pA;
                __syncthreads();
                if (ck + 1 < nchunks) { fetchA(ck + 1); fetchW(ck + 1, n0, n1, n2, n3); }

                h8 a0 = *(const h8*)&A_s[(0  + l15) * 72 + 0  + quad * 8];
                h8 a1 = *(const h8*)&A_s[(16 + l15) * 72 + 0  + quad * 8];
                acc[0][0] = __builtin_amdgcn_mfma_f32_16x16x32_f16(a0, c0,  acc[0][0], 0, 0, 0);
                acc[0][1] = __builtin_amdgcn_mfma_f32_16x16x32_f16(a0, c2r, acc[0][1], 0, 0, 0);
                acc[1][0] = __builtin_amdgcn_mfma_f32_16x16x32_f16(a1, c0,  acc[1][0], 0, 0, 0);
                acc[1][1] = __builtin_amdgcn_mfma_f32_16x16x32_f16(a1, c2r, acc[1][1], 0, 0, 0);
                h8 a2 = *(const h8*)&A_s[(0  + l15) * 72 + 32 + quad * 8];
                h8 a3 = *(const h8*)&A_s[(16 + l15) * 72 + 32 + quad * 8];
                acc[0][0] = __builtin_amdgcn_mfma_f32_16x16x32_f16(a2, c1r, acc[0][0], 0, 0, 0);
                acc[0][1] = __builtin_amdgcn_mfma_f32_16x16x32_f16(a2, c3,  acc[0][1], 0, 0, 0);
                acc[1][0] = __builtin_amdgcn_mfma_f32_16x16x32_f16(a3, c1r, acc[1][0], 0, 0, 0);
                acc[1][1] = __builtin_amdgcn_mfma_f32_16x16x32_f16(a3, c3,  acc[1][1], 0, 0, 0);
                __syncthreads();

                c0 = n0; c1r = n1; c2r = n2; c3 = n3;
            }

            // scatter gates (C/D layout col=lane&15, row=quad*4+reg)
            #pragma unroll
            for (int mt = 0; mt < 2; ++mt)
                #pragma unroll
                for (int nt = 0; nt < 2; ++nt)
                    #pragma unroll
                    for (int r = 0; r < 4; ++r)
                        gate_s[wave][(mt * 16 + quad * 4 + r) * 33 + nt * 16 + l15] = acc[mt][nt][r];
            __syncthreads();

            // cell update: 1024 (b,h) elems, 4/thread
            #pragma unroll
            for (int kk = 0; kk < 4; ++kk) {
                int e = thr + kk * 256;
                int b = e >> 5, col = e & 31;
                float gi = gate_s[0][b * 33 + col];
                float gf = gate_s[1][b * 33 + col];
                float gg = gate_s[2][b * 33 + col];
                float go = gate_s[3][b * 33 + col];
                float si = 1.f / (1.f + __expf(-gi));
                float sf = 1.f / (1.f + __expf(-gf));
                float so = 1.f / (1.f + __expf(-go));
                float tg = tanhf(gg);
                size_t cidx = (size_t)(bt * 32 + b) * H_ + hbase + col;
                float cn = sf * c[cidx] + si * tg;
                c[cidx] = cn;
                float hnv = so * tanhf(cn);
                hn_out[cidx] = (half_t)hnv;
                h_s[b * 33 + col] = hnv;
            }

            if (l1) {
                __syncthreads();
                const float* fcWt = fcW + (size_t)tt * H_;
                for (int p = thr; p < 32 * O_; p += 256) {
                    int o = p >> 5, bb = p & 31;
                    float s = 0.f;
                    #pragma unroll 8
                    for (int j = 0; j < 32; ++j)
                        s += h_s[bb * 33 + j] * fcWt[(size_t)o * (S_ * H_) + hbase + j];
                    out_part[ht * (B_ * O_) + (bt * 32 + bb) * O_ + o] += s;
                }
            }
        }
        grid_barrier(bar_cnt, bar_gen);
    }
}

__global__ void k_final(const float* __restrict__ out_part, const float* __restrict__ fcb,
                        float* __restrict__ out) {
    int i = blockIdx.x * blockDim.x + threadIdx.x;
    if (i >= B_ * O_) return;
    int o = i % O_;
    float s = fcb[o];
    for (int t = 0; t < 32; ++t) s += out_part[t * (B_ * O_) + i];
    out[i] = s;
}

extern "C" void kernel_launch(void* const* d_in, const int* in_sizes, int n_in,
                              void* d_out, int out_size, void* d_ws, size_t ws_size,
                              hipStream_t stream) {
    const float* x    = (const float*)d_in[0];
    const float* Wih0 = (const float*)d_in[1];
    const float* Whh0 = (const float*)d_in[2];
    const float* bih0 = (const float*)d_in[3];
    const float* bhh0 = (const float*)d_in[4];
    const float* Wih1 = (const float*)d_in[5];
    const float* Whh1 = (const float*)d_in[6];
    const float* bih1 = (const float*)d_in[7];
    const float* bhh1 = (const float*)d_in[8];
    const float* fcW  = (const float*)d_in[9];
    const float* fcb  = (const float*)d_in[10];

    char* ws = (char*)d_ws;
    half_t* h1buf  = (half_t*)(ws + OFF_H1);
    half_t* h2buf  = (half_t*)(ws + OFF_H2);
    float*  c1     = (float*)(ws + OFF_C1);
    float*  c2     = (float*)(ws + OFF_C2);
    float*  opart  = (float*)(ws + OFF_OP);
    int*    bar    = (int*)(ws + OFF_BAR);
    float*  bias0  = (float*)(ws + OFF_BIAS0);
    float*  bias1  = (float*)(ws + OFF_BIAS1);
    half_t* x_h    = (half_t*)(ws + OFF_XH);
    half_t* wih0_p = (half_t*)(ws + OFF_WIH0);
    half_t* whh0_p = (half_t*)(ws + OFF_WHH0);
    half_t* wih1_p = (half_t*)(ws + OFF_WIH1);
    half_t* whh1_p = (half_t*)(ws + OFF_WHH1);

    // zero states + FC partials + barrier vars (ws poisoned 0xAA before every launch)
    hipMemsetAsync(d_ws, 0, ZBYTES, stream);

    k_bias<<<dim3((G_ + 255) / 256), dim3(256), 0, stream>>>(bih0, bhh0, bih1, bhh1, bias0, bias1);
    k_cvt<<<dim3(2048), dim3(256), 0, stream>>>(x, x_h, B_ * S_ * F_);
    k_pack<<<dim3(128),  dim3(256), 0, stream>>>(Wih0, wih0_p, 1);
    k_pack<<<dim3(2048), dim3(256), 0, stream>>>(Whh0, whh0_p, 16);
    k_pack<<<dim3(2048), dim3(256), 0, stream>>>(Wih1, wih1_p, 16);
    k_pack<<<dim3(2048), dim3(256), 0, stream>>>(Whh1, whh1_p, 16);

    k_persist<<<dim3(NBLK), dim3(256), 0, stream>>>(x_h,
                                                    wih0_p, whh0_p, bias0, c1, h1buf,
                                                    wih1_p, whh1_p, bias1, c2, h2buf,
                                                    fcW, opart, bar, bar + 64);
    k_final<<<dim3((B_ * O_ + 255) / 256), dim3(256), 0, stream>>>(opart, fcb, (float*)d_out);
}

// Round 8
// 10523.458 us; speedup vs baseline: 5.8005x; 5.8005x over previous
//
#include <hip/hip_runtime.h>
#include <hip/hip_fp16.h>

#define B_ 256
#define S_ 512
#define F_ 64
#define H_ 1024
#define O_ 24
#define G_ 4096  // 4*H

typedef _Float16 half_t;
typedef _Float16 h8 __attribute__((ext_vector_type(8)));
typedef float f4 __attribute__((ext_vector_type(4)));

// ---- workspace layout (bytes) ----
#define OFF_H1 ((size_t)0)                                   // 2*B*H halfs (ping-pong)
#define OFF_H2 (OFF_H1 + (size_t)2*B_*H_*2)
#define OFF_C1 (OFF_H2 + (size_t)2*B_*H_*2)                  // B*H f32
#define OFF_C2 (OFF_C1 + (size_t)B_*H_*4)
#define OFF_OP (OFF_C2 + (size_t)B_*H_*4)                    // out_part [32][B][O] f32
#define ZBYTES (OFF_OP + (size_t)32*B_*O_*4)
#define OFF_BIAS0 (ZBYTES)
#define OFF_BIAS1 (OFF_BIAS0 + (size_t)G_*4)
#define OFF_XH    (OFF_BIAS1 + (size_t)G_*4)                 // B*S*F halfs
#define OFF_WIH0  (OFF_XH + (size_t)B_*S_*F_*2)              // packed, G*F halfs
#define OFF_WHH0  (OFF_WIH0 + (size_t)G_*F_*2)               // packed, G*H halfs
#define OFF_WIH1  (OFF_WHH0 + (size_t)G_*H_*2)
#define OFF_WHH1  (OFF_WIH1 + (size_t)G_*H_*2)
#define WS_NEEDED (OFF_WHH1 + (size_t)G_*H_*2)               // ~47.5 MB

__global__ void k_bias(const float* __restrict__ bi0, const float* __restrict__ bh0,
                       const float* __restrict__ bi1, const float* __restrict__ bh1,
                       float* __restrict__ bias0, float* __restrict__ bias1) {
    int i = blockIdx.x * blockDim.x + threadIdx.x;
    if (i < G_) { bias0[i] = bi0[i] + bh0[i]; bias1[i] = bi1[i] + bh1[i]; }
}

__global__ void k_cvt(const float* __restrict__ src, half_t* __restrict__ dst, int n) {
    int i = blockIdx.x * blockDim.x + threadIdx.x;
    int stride = gridDim.x * blockDim.x;
    for (; i < n; i += stride) dst[i] = (half_t)src[i];
}

// Pack W [4H, NC*64] f32 -> fp16 MFMA-fragment order:
// dst h8 index i = (((g*32+ht)*NC + ck)*4 + j)*64 + lane, j = colhalf*2 + kshalf
__global__ void k_pack(const float* __restrict__ src, half_t* __restrict__ dst, int NC) {
    int i = blockIdx.x * blockDim.x + threadIdx.x;
    int total = 32768 * NC;          // 4*32*NC*4*64
    if (i >= total) return;
    int lane = i & 63;
    int j    = (i >> 6) & 3;
    int ck   = (i >> 8) % NC;
    int gh   = i / (256 * NC);       // g*32+ht, 0..127
    int srow = (gh >> 5) * H_ + (gh & 31) * 32 + (j >> 1) * 16 + (lane & 15);
    int scol = ck * 64 + (j & 1) * 32 + (lane >> 4) * 8;
    const float* s = src + (size_t)srow * (NC * 64) + scol;
    h8 v;
    #pragma unroll
    for (int e = 0; e < 8; ++e) v[e] = (half_t)s[e];
    *(h8*)&dst[(size_t)i * 8] = v;
}

// Fused phase kernel (multi-launch; persistent+grid-barrier measured 5x WORSE:
// agent-scope acquire polls invalidate L2 -> 11 GB HBM refetch, R7 counters).
// Phase t = layer0 step t (blocks 256..511) + layer1 step t-1 (blocks 0..255),
// 2 blocks/CU. Block tile 32b x 32h x 4 gates, wave=gate.
// STAGE-WINDOWED K-loop: stage 8 chunks of A into LDS at once (8 parallel
// loads -> one latency per 8 chunks), 2 barriers per STAGE (not per chunk);
// inner 8-chunk loop is barrier-free. W direct global->VGPR from packed
// fragment-order arrays (1KB coalesced per instr, L2-resident via ht%8==XCD
// map), X/Y named-register ping-pong with compile-time alternation (runtime-
// indexed local arrays go to scratch: round-3's 55x cliff).
__global__ __launch_bounds__(256, 2)
void k_phase(int t,
             const half_t* __restrict__ x_h,
             const half_t* __restrict__ Wih0, const half_t* __restrict__ Whh0,
             const float* __restrict__ bias0, float* __restrict__ c1g, half_t* __restrict__ h1buf,
             const half_t* __restrict__ Wih1, const half_t* __restrict__ Whh1,
             const float* __restrict__ bias1, float* __restrict__ c2g, half_t* __restrict__ h2buf,
             const float* __restrict__ fcW, float* __restrict__ out_part)
{
    // 8-chunk A window [8][32*72] halfs = 36864 B; epilogue LDS unioned on top
    __shared__ __align__(16) char smraw[36864];
    half_t* A_s    = (half_t*)smraw;
    float*  gate_s = (float*)smraw;                  // [4][32*33] = 16896 B
    float*  h_s    = (float*)(smraw + 16896);        // [32*33]    =  4224 B

    const int n  = blockIdx.x;
    const bool l1 = (n < 256);
    const int m  = l1 ? n : n - 256;
    const int ht = (m & 7) + 8 * ((m >> 3) & 3);   // ht % 8 == linear_id % 8 (XCD-resident W)
    const int bt = (m >> 5) & 7;

    int tt; const half_t* xb; int ldx, cx; const half_t* Wih;
    const half_t* Whh; const float* bias; float* c; half_t* hn_out; const half_t* hp;
    if (l1) {
        if (t == 0) return;
        tt = t - 1;
        xb  = h1buf + (size_t)(tt & 1) * B_ * H_;  ldx = H_;      cx = 16;
        Wih = Wih1;  Whh = Whh1;  bias = bias1;  c = c2g;
        hp     = h2buf + (size_t)((tt - 1) & 1) * B_ * H_;
        hn_out = h2buf + (size_t)(tt & 1) * B_ * H_;
    } else {
        if (t >= S_) return;
        tt = t;
        xb  = x_h + (size_t)tt * F_;  ldx = S_ * F_;  cx = 1;
        Wih = Wih0;  Whh = Whh0;  bias = bias0;  c = c1g;
        hp     = h1buf + (size_t)((tt - 1) & 1) * B_ * H_;
        hn_out = h1buf + (size_t)(tt & 1) * B_ * H_;
    }

    const int thr  = threadIdx.x;
    const int wave = thr >> 6, lane = thr & 63;
    const int quad = lane >> 4, l15 = lane & 15;
    const int hbase = ht * 32;

    // bias folded into accumulator init (col = nt*16 + l15)
    float bv0 = bias[wave * H_ + hbase + l15];
    float bv1 = bias[wave * H_ + hbase + 16 + l15];
    f4 acc[2][2];
    #pragma unroll
    for (int mt = 0; mt < 2; ++mt) {
        acc[mt][0] = (f4){bv0, bv0, bv0, bv0};
        acc[mt][1] = (f4){bv1, bv1, bv1, bv1};
    }

    const int nchunks = cx + 16;            // K = cx*64 + 1024 (l0:17, l1:32)
    const int ghW = wave * 32 + ht;         // packed-W (gate,ht) group
    const int ar  = thr >> 3;               // A staging row 0..31
    const int ak  = (thr & 7) * 8;          // A staging k-offset

    auto loadA = [&](int ck) -> f4 {
        const half_t* Ab; int lda, k0;
        if (ck < cx) { Ab = xb; lda = ldx; k0 = ck * 64; }
        else         { Ab = hp; lda = H_;  k0 = (ck - cx) * 64; }
        return *(const f4*)&Ab[(size_t)(bt * 32 + ar) * lda + k0 + ak];
    };
    auto fetchW = [&](int ck, h8& r0, h8& r1, h8& r2, h8& r3) {
        const half_t* Wb; int ckk, NC;
        if (ck < cx) { Wb = Wih; ckk = ck;      NC = cx; }
        else         { Wb = Whh; ckk = ck - cx; NC = 16; }
        const half_t* base = Wb + ((size_t)(((ghW * NC) + ckk) * 4) * 64 + lane) * 8;
        r0 = *(const h8*)(base + 0 * 512);
        r1 = *(const h8*)(base + 1 * 512);
        r2 = *(const h8*)(base + 2 * 512);
        r3 = *(const h8*)(base + 3 * 512);
    };

    for (int s = 0; s < nchunks; s += 8) {
        const int ns = (nchunks - s < 8) ? (nchunks - s) : 8;   // block-uniform

        // ---- fill: 8 parallel loads (one latency for the whole window) ----
        f4 p0, p1, p2, p3, p4, p5, p6, p7;
        /*always*/      p0 = loadA(s + 0);
        if (ns > 1)     p1 = loadA(s + 1);
        if (ns > 2)     p2 = loadA(s + 2);
        if (ns > 3)     p3 = loadA(s + 3);
        if (ns > 4)     p4 = loadA(s + 4);
        if (ns > 5)     p5 = loadA(s + 5);
        if (ns > 6)     p6 = loadA(s + 6);
        if (ns > 7)     p7 = loadA(s + 7);
        __syncthreads();   // previous window's readers done
        /*always*/      *(f4*)&A_s[0 * 2304 + ar * 72 + ak] = p0;
        if (ns > 1)     *(f4*)&A_s[1 * 2304 + ar * 72 + ak] = p1;
        if (ns > 2)     *(f4*)&A_s[2 * 2304 + ar * 72 + ak] = p2;
        if (ns > 3)     *(f4*)&A_s[3 * 2304 + ar * 72 + ak] = p3;
        if (ns > 4)     *(f4*)&A_s[4 * 2304 + ar * 72 + ak] = p4;
        if (ns > 5)     *(f4*)&A_s[5 * 2304 + ar * 72 + ak] = p5;
        if (ns > 6)     *(f4*)&A_s[6 * 2304 + ar * 72 + ak] = p6;
        if (ns > 7)     *(f4*)&A_s[7 * 2304 + ar * 72 + ak] = p7;
        __syncthreads();   // window visible

        // ---- compute ns chunks, barrier-free; W ping-pong X/Y ----
        h8 xw0, xw1, xw2, xw3, yw0, yw1, yw2, yw3;
        fetchW(s, xw0, xw1, xw2, xw3);

        #define STEP(i, C0,C1,C2,C3, N0,N1,N2,N3)                                              \
        if (i < ns) {                                                                          \
            if (i + 1 < ns) fetchW(s + i + 1, N0, N1, N2, N3);                                 \
            h8 a0 = *(const h8*)&A_s[i * 2304 + (0  + l15) * 72 + 0  + quad * 8];              \
            h8 a1 = *(const h8*)&A_s[i * 2304 + (16 + l15) * 72 + 0  + quad * 8];              \
            h8 a2 = *(const h8*)&A_s[i * 2304 + (0  + l15) * 72 + 32 + quad * 8];              \
            h8 a3 = *(const h8*)&A_s[i * 2304 + (16 + l15) * 72 + 32 + quad * 8];              \
            acc[0][0] = __builtin_amdgcn_mfma_f32_16x16x32_f16(a0, C0, acc[0][0], 0,0,0);      \
            acc[0][1] = __builtin_amdgcn_mfma_f32_16x16x32_f16(a0, C2, acc[0][1], 0,0,0);      \
            acc[1][0] = __builtin_amdgcn_mfma_f32_16x16x32_f16(a1, C0, acc[1][0], 0,0,0);      \
            acc[1][1] = __builtin_amdgcn_mfma_f32_16x16x32_f16(a1, C2, acc[1][1], 0,0,0);      \
            acc[0][0] = __builtin_amdgcn_mfma_f32_16x16x32_f16(a2, C1, acc[0][0], 0,0,0);      \
            acc[0][1] = __builtin_amdgcn_mfma_f32_16x16x32_f16(a2, C3, acc[0][1], 0,0,0);      \
            acc[1][0] = __builtin_amdgcn_mfma_f32_16x16x32_f16(a3, C1, acc[1][0], 0,0,0);      \
            acc[1][1] = __builtin_amdgcn_mfma_f32_16x16x32_f16(a3, C3, acc[1][1], 0,0,0);      \
        }
        STEP(0, xw0,xw1,xw2,xw3, yw0,yw1,yw2,yw3)
        STEP(1, yw0,yw1,yw2,yw3, xw0,xw1,xw2,xw3)
        STEP(2, xw0,xw1,xw2,xw3, yw0,yw1,yw2,yw3)
        STEP(3, yw0,yw1,yw2,yw3, xw0,xw1,xw2,xw3)
        STEP(4, xw0,xw1,xw2,xw3, yw0,yw1,yw2,yw3)
        STEP(5, yw0,yw1,yw2,yw3, xw0,xw1,xw2,xw3)
        STEP(6, xw0,xw1,xw2,xw3, yw0,yw1,yw2,yw3)
        STEP(7, yw0,yw1,yw2,yw3, xw0,xw1,xw2,xw3)
        #undef STEP
    }

    __syncthreads();   // all waves done reading A window before LDS reuse

    // scatter gates (C/D layout col=lane&15, row=quad*4+reg)
    #pragma unroll
    for (int mt = 0; mt < 2; ++mt)
        #pragma unroll
        for (int nt = 0; nt < 2; ++nt)
            #pragma unroll
            for (int r = 0; r < 4; ++r)
                gate_s[wave * (32 * 33) + (mt * 16 + quad * 4 + r) * 33 + nt * 16 + l15] = acc[mt][nt][r];
    __syncthreads();

    // cell update: 1024 (b,h) elems, 4/thread
    #pragma unroll
    for (int kk = 0; kk < 4; ++kk) {
        int e = thr + kk * 256;
        int b = e >> 5, col = e & 31;
        float gi = gate_s[0 * (32 * 33) + b * 33 + col];
        float gf = gate_s[1 * (32 * 33) + b * 33 + col];
        float gg = gate_s[2 * (32 * 33) + b * 33 + col];
        float go = gate_s[3 * (32 * 33) + b * 33 + col];
        float si = 1.f / (1.f + __expf(-gi));
        float sf = 1.f / (1.f + __expf(-gf));
        float so = 1.f / (1.f + __expf(-go));
        float tg = tanhf(gg);
        size_t cidx = (size_t)(bt * 32 + b) * H_ + hbase + col;
        float cn = sf * c[cidx] + si * tg;
        c[cidx] = cn;
        float hnv = so * tanhf(cn);
        hn_out[cidx] = (half_t)hnv;
        h_s[b * 33 + col] = hnv;
    }

    if (l1) {
        __syncthreads();
        const float* fcWt = fcW + (size_t)tt * H_;
        for (int p = thr; p < 32 * O_; p += 256) {
            int o = p >> 5, bb = p & 31;
            float s2 = 0.f;
            #pragma unroll 8
            for (int j = 0; j < 32; ++j)
                s2 += h_s[bb * 33 + j] * fcWt[(size_t)o * (S_ * H_) + hbase + j];
            out_part[ht * (B_ * O_) + (bt * 32 + bb) * O_ + o] += s2;
        }
    }
}

__global__ void k_final(const float* __restrict__ out_part, const float* __restrict__ fcb,
                        float* __restrict__ out) {
    int i = blockIdx.x * blockDim.x + threadIdx.x;
    if (i >= B_ * O_) return;
    int o = i % O_;
    float s = fcb[o];
    for (int t = 0; t < 32; ++t) s += out_part[t * (B_ * O_) + i];
    out[i] = s;
}

extern "C" void kernel_launch(void* const* d_in, const int* in_sizes, int n_in,
                              void* d_out, int out_size, void* d_ws, size_t ws_size,
                              hipStream_t stream) {
    const float* x    = (const float*)d_in[0];
    const float* Wih0 = (const float*)d_in[1];
    const float* Whh0 = (const float*)d_in[2];
    const float* bih0 = (const float*)d_in[3];
    const float* bhh0 = (const float*)d_in[4];
    const float* Wih1 = (const float*)d_in[5];
    const float* Whh1 = (const float*)d_in[6];
    const float* bih1 = (const float*)d_in[7];
    const float* bhh1 = (const float*)d_in[8];
    const float* fcW  = (const float*)d_in[9];
    const float* fcb  = (const float*)d_in[10];

    char* ws = (char*)d_ws;
    half_t* h1buf  = (half_t*)(ws + OFF_H1);
    half_t* h2buf  = (half_t*)(ws + OFF_H2);
    float*  c1     = (float*)(ws + OFF_C1);
    float*  c2     = (float*)(ws + OFF_C2);
    float*  opart  = (float*)(ws + OFF_OP);
    float*  bias0  = (float*)(ws + OFF_BIAS0);
    float*  bias1  = (float*)(ws + OFF_BIAS1);
    half_t* x_h    = (half_t*)(ws + OFF_XH);
    half_t* wih0_p = (half_t*)(ws + OFF_WIH0);
    half_t* whh0_p = (half_t*)(ws + OFF_WHH0);
    half_t* wih1_p = (half_t*)(ws + OFF_WIH1);
    half_t* whh1_p = (half_t*)(ws + OFF_WHH1);

    // zero states + FC partials (ws poisoned 0xAA before every launch)
    hipMemsetAsync(d_ws, 0, ZBYTES, stream);

    k_bias<<<dim3((G_ + 255) / 256), dim3(256), 0, stream>>>(bih0, bhh0, bih1, bhh1, bias0, bias1);
    k_cvt<<<dim3(2048), dim3(256), 0, stream>>>(x, x_h, B_ * S_ * F_);
    k_pack<<<dim3(128),  dim3(256), 0, stream>>>(Wih0, wih0_p, 1);
    k_pack<<<dim3(2048), dim3(256), 0, stream>>>(Whh0, whh0_p, 16);
    k_pack<<<dim3(2048), dim3(256), 0, stream>>>(Wih1, wih1_p, 16);
    k_pack<<<dim3(2048), dim3(256), 0, stream>>>(Whh1, whh1_p, 16);

    dim3 grid(512), blk(256);
    for (int t = 0; t <= S_; ++t) {
        k_phase<<<grid, blk, 0, stream>>>(t, x_h,
                                          wih0_p, whh0_p, bias0, c1, h1buf,
                                          wih1_p, whh1_p, bias1, c2, h2buf,
                                          fcW, opart);
    }
    k_final<<<dim3((B_ * O_ + 255) / 256), dim3(256), 0, stream>>>(opart, fcb, (float*)d_out);
}